// Round 8
// baseline (286.205 us; speedup 1.0000x reference)
//
#include <hip/hip_runtime.h>

typedef __attribute__((ext_vector_type(8))) short bf16x8;     // 8 bf16 in 4 VGPRs
typedef __attribute__((ext_vector_type(4))) short bf16x4;     // 4 bf16 in 2 VGPRs
typedef __attribute__((ext_vector_type(8))) unsigned short u16x8;
typedef __attribute__((ext_vector_type(4))) float f32x4;
typedef __attribute__((ext_vector_type(2))) unsigned int u32x2;

__device__ __forceinline__ unsigned short f2b(float f) {      // f32 -> bf16 RNE
  unsigned int u = __builtin_bit_cast(unsigned int, f);
  u += 0x7FFFu + ((u >> 16) & 1u);
  return (unsigned short)(u >> 16);
}
__device__ __forceinline__ float b2f(unsigned short h) {
  return __builtin_bit_cast(float, ((unsigned int)h) << 16);
}

__device__ __forceinline__ f32x4 mfma16x16x16(bf16x4 a, bf16x4 b, f32x4 c) {
#if __has_builtin(__builtin_amdgcn_mfma_f32_16x16x16bf16_1k)
  return __builtin_amdgcn_mfma_f32_16x16x16bf16_1k(a, b, c, 0, 0, 0);
#else
  asm volatile("v_mfma_f32_16x16x16_bf16 %0, %1, %2, %0" : "+v"(c) : "v"(a), "v"(b));
  return c;
#endif
}

// pack 4 f32 -> bf16x4 via v_cvt_pk_bf16_f32 (RNE, 2 insts)
__device__ __forceinline__ bf16x4 pack4(float a, float b, float c, float d) {
  unsigned int lo, hi;
  asm("v_cvt_pk_bf16_f32 %0, %1, %2" : "=v"(lo) : "v"(a), "v"(b));
  asm("v_cvt_pk_bf16_f32 %0, %1, %2" : "=v"(hi) : "v"(c), "v"(d));
  u32x2 u = {lo, hi};
  return __builtin_bit_cast(bf16x4, u);
}

#define AS1(p) (const __attribute__((address_space(1))) void*)(p)
#define AS3(p) (__attribute__((address_space(3))) void*)(p)

// ---------------- merged f32 -> bf16 convert (5 segments) ----------------
__device__ __forceinline__ void cvt8(const float* __restrict__ in,
                                     unsigned short* __restrict__ out,
                                     int i, float scale) {
  const float4* p = (const float4*)in + (size_t)i * 2;
  float4 a = p[0], b = p[1];
  u16x8 r;
  r[0] = f2b(a.x * scale); r[1] = f2b(a.y * scale);
  r[2] = f2b(a.z * scale); r[3] = f2b(a.w * scale);
  r[4] = f2b(b.x * scale); r[5] = f2b(b.y * scale);
  r[6] = f2b(b.z * scale); r[7] = f2b(b.w * scale);
  *((u16x8*)out + i) = r;
}

__global__ __launch_bounds__(256) void k_cvt_all(
    const float* __restrict__ x,  const float* __restrict__ Wq,
    const float* __restrict__ Wk, const float* __restrict__ Wv,
    const float* __restrict__ Wo, unsigned short* __restrict__ xb,
    unsigned short* __restrict__ wqkv, unsigned short* __restrict__ Wob,
    float sc) {
  int bid = blockIdx.x;                      // 9216 blocks total, 2048 elems each
  int tid = threadIdx.x;
  if (bid < 4096)      cvt8(x,  xb,             (bid        ) * 256 + tid, 1.f);
  else if (bid < 6144) cvt8(Wq, wqkv,           (bid - 4096) * 256 + tid, sc);
  else if (bid < 6656) cvt8(Wk, wqkv + 4194304, (bid - 6144) * 256 + tid, 1.f);
  else if (bid < 7168) cvt8(Wv, wqkv + 5242880, (bid - 6656) * 256 + tid, 1.f);
  else                 cvt8(Wo, Wob,            (bid - 7168) * 256 + tid, 1.f);
}

// ---------------- merged RoPE (q/k cols) + V transpose ----------------
__global__ __launch_bounds__(256) void k_post(unsigned short* __restrict__ qkv,
                                              const float* __restrict__ cosb,
                                              const float* __restrict__ sinb,
                                              unsigned short* __restrict__ vT) {
  __shared__ unsigned short tile[64][72];
  const int bid = blockIdx.x, t = threadIdx.x;
  if (bid < 2560) {
    int tid = bid * 256 + t;                 // 4096*20*8 = 655360
    int oct = tid & 7;
    int hd  = (tid >> 3) % 20;
    int s   = (tid >> 3) / 20;
    unsigned short* p1 = qkv + (size_t)s * 3072 + hd * 128 + oct * 8;
    unsigned short* p2 = p1 + 64;
    u16x8 a = *(const u16x8*)p1;
    u16x8 b = *(const u16x8*)p2;
    const float4* cp = (const float4*)(cosb + (size_t)s * 128 + oct * 8);
    const float4* sp = (const float4*)(sinb + (size_t)s * 128 + oct * 8);
    float4 c0 = cp[0], c1 = cp[1], s0 = sp[0], s1 = sp[1];
    float cs[8] = {c0.x,c0.y,c0.z,c0.w,c1.x,c1.y,c1.z,c1.w};
    float sn[8] = {s0.x,s0.y,s0.z,s0.w,s1.x,s1.y,s1.z,s1.w};
    u16x8 ra, rb;
#pragma unroll
    for (int j = 0; j < 8; ++j) {
      float av = b2f(a[j]), bv = b2f(b[j]);
      ra[j] = f2b(av * cs[j] - bv * sn[j]);
      rb[j] = f2b(bv * cs[j] + av * sn[j]);
    }
    *(u16x8*)p1 = ra;
    *(u16x8*)p2 = rb;
  } else {
    int idx = bid - 2560;                    // 512 tiles
    int bs = idx >> 3, bc = idx & 7;
#pragma unroll
    for (int i = 0; i < 2; ++i) {
      int c8 = t + 256 * i;                  // 0..511
      int row = c8 >> 3, cb = c8 & 7;
      u16x8 v = *(const u16x8*)(qkv + (size_t)(bs * 64 + row) * 3072 + 2560 + bc * 64 + cb * 8);
#pragma unroll
      for (int j = 0; j < 8; ++j) tile[row][cb * 8 + j] = v[j];
    }
    __syncthreads();
#pragma unroll
    for (int i = 0; i < 2; ++i) {
      int c8 = t + 256 * i;
      int crow = c8 >> 3, sb = c8 & 7;
      u16x8 v;
#pragma unroll
      for (int j = 0; j < 8; ++j) v[j] = tile[sb * 8 + j][crow];
      *(u16x8*)(vT + (size_t)(bc * 64 + crow) * 4096 + bs * 64 + sb * 8) = v;
    }
  }
}

// ---------------- GEMM C[M,N] = A[M,K] @ B[N,K]^T (bf16 in, bf16/f32 out) --
template <int OUTF32>
__global__ __launch_bounds__(256) void k_gemm_bt(
    const unsigned short* __restrict__ A, const unsigned short* __restrict__ B,
    void* __restrict__ C, int K, int lda, int ldb, int ldc) {
  __shared__ unsigned short As[128 * 64];
  __shared__ unsigned short Bs[128 * 64];
  const int t = threadIdx.x;
  const int lane = t & 63, w = t >> 6;
  const int wm = w >> 1, wn = w & 1;
  const int bn = blockIdx.x, bm = blockIdx.y;
  const unsigned short* Arow = A + (size_t)(bm * 128) * lda;
  const unsigned short* Brow = B + (size_t)(bn * 128) * ldb;

  f32x4 acc[4][4] = {};
  for (int kt = 0; kt < K; kt += 64) {
#pragma unroll
    for (int i = 0; i < 4; ++i) {
      int idx = i * 256 + t;
      int r = idx >> 3, blk = idx & 7;
      int sb = blk ^ (r & 7);
      __builtin_amdgcn_global_load_lds(AS1(Arow + (size_t)r * lda + kt + sb * 8),
                                       AS3(As + (i * 256 + w * 64) * 8), 16, 0, 0);
    }
#pragma unroll
    for (int i = 0; i < 4; ++i) {
      int idx = i * 256 + t;
      int r = idx >> 3, blk = idx & 7;
      int sb = blk ^ (r & 7);
      __builtin_amdgcn_global_load_lds(AS1(Brow + (size_t)r * ldb + kt + sb * 8),
                                       AS3(Bs + (i * 256 + w * 64) * 8), 16, 0, 0);
    }
    __syncthreads();
#pragma unroll
    for (int kk = 0; kk < 2; ++kk) {
      bf16x8 av[4], bv[4];
#pragma unroll
      for (int i = 0; i < 4; ++i) {
        int r = wm * 64 + i * 16 + (lane & 15);
        int off = (r * 128 + (kk * 32 + (lane >> 4) * 8) * 2) ^ ((r & 7) << 4);
        av[i] = *(const bf16x8*)((const char*)As + off);
      }
#pragma unroll
      for (int j = 0; j < 4; ++j) {
        int r = wn * 64 + j * 16 + (lane & 15);
        int off = (r * 128 + (kk * 32 + (lane >> 4) * 8) * 2) ^ ((r & 7) << 4);
        bv[j] = *(const bf16x8*)((const char*)Bs + off);
      }
#pragma unroll
      for (int i = 0; i < 4; ++i)
#pragma unroll
        for (int j = 0; j < 4; ++j)
          acc[i][j] = __builtin_amdgcn_mfma_f32_16x16x32_bf16(av[i], bv[j], acc[i][j], 0, 0, 0);
    }
    __syncthreads();
  }
#pragma unroll
  for (int i = 0; i < 4; ++i)
#pragma unroll
    for (int j = 0; j < 4; ++j)
#pragma unroll
      for (int r = 0; r < 4; ++r) {
        int m = bm * 128 + wm * 64 + i * 16 + (lane >> 4) * 4 + r;
        int n = bn * 128 + wn * 64 + j * 16 + (lane & 15);
        float v = acc[i][j][r];
        if (OUTF32) ((float*)C)[(size_t)m * ldc + n] = v;
        else        ((unsigned short*)C)[(size_t)m * ldc + n] = f2b(v);
      }
}

// ---------------- fused causal GQA flash attention ----------------
// r6-proven skeleton (64-row q tile, dbuf K/V, swapped QK^T, register P,
// row-sum via MFMA(ones), one masked peel) + TWO HEADS of the same GQA
// group per block: identical K/V tiles and mask serve both heads, so each
// LDS read feeds 2 MFMAs -> LDS traffic per unit work halved (kernel was
// LDS-BW-bound). Grid (64 qt, 8 head-pairs) = 512 blocks, LPT order.
__global__ __launch_bounds__(256, 2) void k_attn(const unsigned short* __restrict__ qk,
                                                 const unsigned short* __restrict__ vT,
                                                 unsigned short* __restrict__ ctx) {
  __shared__ unsigned short Ks[2][64 * 128];
  __shared__ unsigned short Vs[2][64 * 128];
  const int qt = 63 - (int)blockIdx.x;       // LPT: longest first
  const int hp = blockIdx.y;                 // head pair: heads 2hp, 2hp+1
  const int h0 = hp * 2, g = hp >> 1;        // same KV group for both heads
  const int t = threadIdx.x, lane = t & 63, w = t >> 6;
  const int l15 = lane & 15, lq = lane >> 4;
  const int xv = (l15 & 7) << 4;             // swizzle XOR field (lane-constant)
  const int qg = qt * 64 + w * 16 + l15;     // this lane's softmax q-row (global)

  // LDS read bases: K addr = kb[sl] + nt*4096, V addr = vb[nt] + dt*2048
  int kb[4], vb[4];
#pragma unroll
  for (int sl = 0; sl < 4; ++sl) kb[sl] = ((sl * 64 + lq * 16) ^ xv) + l15 * 256;
#pragma unroll
  for (int nt = 0; nt < 4; ++nt) vb[nt] = ((nt * 32 + lq * 8) ^ xv) + l15 * 128;

  const bf16x4 ones = { (short)0x3F80, (short)0x3F80, (short)0x3F80, (short)0x3F80 };

  // staging pointers (strength-reduced: advance per tile)
  const unsigned short* kgp[4];
  const unsigned short* vgp[4];
  unsigned short* kld[4];
  unsigned short* vld[4];
#pragma unroll
  for (int i = 0; i < 4; ++i) {
    int idx = i * 256 + t;
    int r = idx >> 4, blk = idx & 15;
    int sb = (blk & 8) | ((blk ^ r) & 7);
    kgp[i] = qk + (size_t)r * 3072 + 2048 + g * 128 + sb * 8;
    kld[i] = (unsigned short*)Ks[0] + (size_t)(i * 256 + w * 64) * 8;
    int r2 = idx >> 3, blk2 = idx & 7;
    int sb2 = blk2 ^ (r2 & 7);
    vgp[i] = vT + (size_t)(g * 128 + r2) * 4096 + sb2 * 8;
    vld[i] = (unsigned short*)Vs[0] + (size_t)(i * 256 + w * 64) * 8;
  }

  // Q fragments for both heads (B-operand: col=l15, k-chunk by lq)
  bf16x8 aq0[4], aq1[4];
  {
    const unsigned short* qb =
        qk + (size_t)(qt * 64 + w * 16 + l15) * 3072 + h0 * 128 + lq * 8;
#pragma unroll
    for (int sl = 0; sl < 4; ++sl) {
      aq0[sl] = *(const bf16x8*)(qb + sl * 32);
      aq1[sl] = *(const bf16x8*)(qb + 128 + sl * 32);
    }
  }
  f32x4 o0[8] = {}, o1[8] = {};
  f32x4 osum0 = {}, osum1 = {};
  bf16x4 pa0[4], pa1[4];

  // prologue: stage tile 0 into parity 0
#pragma unroll
  for (int i = 0; i < 4; ++i) {
    __builtin_amdgcn_global_load_lds(AS1(kgp[i]), AS3(kld[i]), 16, 0, 0);
    __builtin_amdgcn_global_load_lds(AS1(vgp[i]), AS3(vld[i]), 16, 0, 0);
    kgp[i] += 64 * 3072;
    vgp[i] += 64;
  }
  asm volatile("s_waitcnt vmcnt(0)" ::: "memory");
  __builtin_amdgcn_s_barrier();

#define TILE(PAR, KT, MASKT)                                                   \
  {                                                                            \
    const char* Kc = (const char*)Ks[PAR];                                     \
    const char* Vc = (const char*)Vs[PAR];                                     \
    f32x4 st0[4] = {}, st1[4] = {};                                            \
    __builtin_amdgcn_s_setprio(1);                                             \
    _Pragma("unroll")                                                          \
    for (int sl = 0; sl < 4; ++sl)                                             \
      _Pragma("unroll")                                                        \
      for (int nt = 0; nt < 4; ++nt) {                                         \
        bf16x8 bk = *(const bf16x8*)(Kc + kb[sl] + nt * 4096);                 \
        st0[nt] = __builtin_amdgcn_mfma_f32_16x16x32_bf16(bk, aq0[sl], st0[nt], 0, 0, 0); \
        st1[nt] = __builtin_amdgcn_mfma_f32_16x16x32_bf16(bk, aq1[sl], st1[nt], 0, 0, 0); \
      }                                                                        \
    __builtin_amdgcn_s_setprio(0);                                             \
    _Pragma("unroll")                                                          \
    for (int nt = 0; nt < 4; ++nt) {                                           \
      float q0[4], q1[4];                                                      \
      _Pragma("unroll")                                                        \
      for (int r = 0; r < 4; ++r) {                                            \
        q0[r] = __builtin_amdgcn_exp2f(st0[nt][r]);                            \
        q1[r] = __builtin_amdgcn_exp2f(st1[nt][r]);                            \
        if (MASKT) {                                                           \
          int key = (KT) * 64 + nt * 16 + lq * 4 + r;                          \
          if (key > qg) { q0[r] = 0.f; q1[r] = 0.f; }                          \
        }                                                                      \
      }                                                                        \
      pa0[nt] = pack4(q0[0], q0[1], q0[2], q0[3]);                             \
      pa1[nt] = pack4(q1[0], q1[1], q1[2], q1[3]);                             \
    }                                                                          \
    __builtin_amdgcn_s_setprio(1);                                             \
    _Pragma("unroll")                                                          \
    for (int nt = 0; nt < 4; ++nt) {                                           \
      osum0 = mfma16x16x16(pa0[nt], ones, osum0);                              \
      osum1 = mfma16x16x16(pa1[nt], ones, osum1);                              \
      _Pragma("unroll")                                                        \
      for (int dt = 0; dt < 8; ++dt) {                                         \
        bf16x4 vv = *(const bf16x4*)(Vc + vb[nt] + dt * 2048);                 \
        o0[dt] = mfma16x16x16(pa0[nt], vv, o0[dt]);                            \
        o1[dt] = mfma16x16x16(pa1[nt], vv, o1[dt]);                            \
      }                                                                        \
    }                                                                          \
    __builtin_amdgcn_s_setprio(0);                                             \
  }

  for (int kt = 0; kt < qt; ++kt) {          // unmasked main loop
    const int cur = kt & 1, nb = cur ^ 1;
#pragma unroll
    for (int i = 0; i < 4; ++i) {            // prefetch tile kt+1
      __builtin_amdgcn_global_load_lds(AS1(kgp[i]), AS3(kld[i] + nb * 8192), 16, 0, 0);
      __builtin_amdgcn_global_load_lds(AS1(vgp[i]), AS3(vld[i] + nb * 8192), 16, 0, 0);
      kgp[i] += 64 * 3072;
      vgp[i] += 64;
    }
    TILE(cur, kt, false)
    asm volatile("s_waitcnt vmcnt(0)" ::: "memory");  // prefetch landed
    __builtin_amdgcn_s_barrier();
  }
  TILE(qt & 1, qt, true)                     // peeled masked diagonal tile
#undef TILE

  // ---- epilogue: osum[r] is the row sum for q-row lq*4+r (MFMA D-layout) ---
  float iq0[4], iq1[4];
#pragma unroll
  for (int r = 0; r < 4; ++r) { iq0[r] = 1.f / osum0[r]; iq1[r] = 1.f / osum1[r]; }
#pragma unroll
  for (int dt = 0; dt < 8; ++dt)
#pragma unroll
    for (int r = 0; r < 4; ++r) {
      int q = qt * 64 + w * 16 + lq * 4 + r;
      int c = h0 * 128 + dt * 16 + l15;
      ctx[(size_t)q * 2048 + c]       = f2b(o0[dt][r] * iq0[r]);
      ctx[(size_t)q * 2048 + c + 128] = f2b(o1[dt][r] * iq1[r]);
    }
}

// ---------------- host ----------------
extern "C" void kernel_launch(void* const* d_in, const int* in_sizes, int n_in,
                              void* d_out, int out_size, void* d_ws, size_t ws_size,
                              hipStream_t stream) {
  const float* x    = (const float*)d_in[0];
  const float* cosb = (const float*)d_in[2];
  const float* sinb = (const float*)d_in[3];
  const float* Wq   = (const float*)d_in[4];
  const float* Wk   = (const float*)d_in[5];
  const float* Wv   = (const float*)d_in[6];
  const float* Wo   = (const float*)d_in[7];

  char* p = (char*)d_ws;
  unsigned short* xb   = (unsigned short*)p; p += (size_t)8388608 * 2;   // x bf16
  unsigned short* wqkv = (unsigned short*)p; p += (size_t)6291456 * 2;   // [3072][2048]
  unsigned short* Wob  = (unsigned short*)p; p += (size_t)4194304 * 2;
  unsigned short* qkvb = (unsigned short*)p; p += (size_t)4096 * 3072 * 2;
  unsigned short* vTb  = (unsigned short*)p; p += (size_t)512 * 4096 * 2;
  unsigned short* ctx  = (unsigned short*)p; p += (size_t)4096 * 2048 * 2;
  if (ws_size < (size_t)(p - (char*)d_ws)) return;

  const float SC = 0.12751741f;   // (1/sqrt(128)) * log2(e), folded into Wq

  k_cvt_all<<<9216, 256, 0, stream>>>(x, Wq, Wk, Wv, Wo, xb, wqkv, Wob, SC);

  // qkv = x @ [Wq;Wk;Wv]^T  -> [4096][3072] (q:0-2047, k:2048-2559, v:2560-3071)
  k_gemm_bt<0><<<dim3(24, 32), 256, 0, stream>>>(xb, wqkv, qkvb, 2048, 2048, 2048, 3072);

  k_post<<<3072, 256, 0, stream>>>(qkvb, cosb, sinb, vTb);

  k_attn<<<dim3(64, 8), 256, 0, stream>>>(qkvb, vTb, ctx);

  k_gemm_bt<1><<<dim3(16, 32), 256, 0, stream>>>(ctx, Wob, d_out, 2048, 2048, 2048, 2048);
}

// Round 9
// 263.560 us; speedup vs baseline: 1.0859x; 1.0859x over previous
//
#include <hip/hip_runtime.h>

typedef __attribute__((ext_vector_type(8))) short bf16x8;     // 8 bf16 in 4 VGPRs
typedef __attribute__((ext_vector_type(4))) short bf16x4;     // 4 bf16 in 2 VGPRs
typedef __attribute__((ext_vector_type(8))) unsigned short u16x8;
typedef __attribute__((ext_vector_type(4))) float f32x4;

__device__ __forceinline__ unsigned short f2b(float f) {      // f32 -> bf16 RNE
  unsigned int u = __builtin_bit_cast(unsigned int, f);
  u += 0x7FFFu + ((u >> 16) & 1u);
  return (unsigned short)(u >> 16);
}
__device__ __forceinline__ float b2f(unsigned short h) {
  return __builtin_bit_cast(float, ((unsigned int)h) << 16);
}

__device__ __forceinline__ f32x4 mfma16x16x16(bf16x4 a, bf16x4 b, f32x4 c) {
#if __has_builtin(__builtin_amdgcn_mfma_f32_16x16x16bf16_1k)
  return __builtin_amdgcn_mfma_f32_16x16x16bf16_1k(a, b, c, 0, 0, 0);
#else
  asm volatile("v_mfma_f32_16x16x16_bf16 %0, %1, %2, %0" : "+v"(c) : "v"(a), "v"(b));
  return c;
#endif
}

#define AS1(p) (const __attribute__((address_space(1))) void*)(p)
#define AS3(p) (__attribute__((address_space(3))) void*)(p)

// ---------------- merged f32 -> bf16 convert (5 segments) ----------------
__device__ __forceinline__ void cvt8(const float* __restrict__ in,
                                     unsigned short* __restrict__ out,
                                     int i, float scale) {
  const float4* p = (const float4*)in + (size_t)i * 2;
  float4 a = p[0], b = p[1];
  u16x8 r;
  r[0] = f2b(a.x * scale); r[1] = f2b(a.y * scale);
  r[2] = f2b(a.z * scale); r[3] = f2b(a.w * scale);
  r[4] = f2b(b.x * scale); r[5] = f2b(b.y * scale);
  r[6] = f2b(b.z * scale); r[7] = f2b(b.w * scale);
  *((u16x8*)out + i) = r;
}

__global__ __launch_bounds__(256) void k_cvt_all(
    const float* __restrict__ x,  const float* __restrict__ Wq,
    const float* __restrict__ Wk, const float* __restrict__ Wv,
    const float* __restrict__ Wo, unsigned short* __restrict__ xb,
    unsigned short* __restrict__ wqkv, unsigned short* __restrict__ Wob,
    float sc) {
  int bid = blockIdx.x;                      // 9216 blocks total, 2048 elems each
  int tid = threadIdx.x;
  if (bid < 4096)      cvt8(x,  xb,             (bid        ) * 256 + tid, 1.f);
  else if (bid < 6144) cvt8(Wq, wqkv,           (bid - 4096) * 256 + tid, sc);
  else if (bid < 6656) cvt8(Wk, wqkv + 4194304, (bid - 6144) * 256 + tid, 1.f);
  else if (bid < 7168) cvt8(Wv, wqkv + 5242880, (bid - 6656) * 256 + tid, 1.f);
  else                 cvt8(Wo, Wob,            (bid - 7168) * 256 + tid, 1.f);
}

// ---------------- merged RoPE (q/k cols) + V transpose ----------------
__global__ __launch_bounds__(256) void k_post(unsigned short* __restrict__ qkv,
                                              const float* __restrict__ cosb,
                                              const float* __restrict__ sinb,
                                              unsigned short* __restrict__ vT) {
  __shared__ unsigned short tile[64][72];
  const int bid = blockIdx.x, t = threadIdx.x;
  if (bid < 2560) {
    int tid = bid * 256 + t;                 // 4096*20*8 = 655360
    int oct = tid & 7;
    int hd  = (tid >> 3) % 20;
    int s   = (tid >> 3) / 20;
    unsigned short* p1 = qkv + (size_t)s * 3072 + hd * 128 + oct * 8;
    unsigned short* p2 = p1 + 64;
    u16x8 a = *(const u16x8*)p1;
    u16x8 b = *(const u16x8*)p2;
    const float4* cp = (const float4*)(cosb + (size_t)s * 128 + oct * 8);
    const float4* sp = (const float4*)(sinb + (size_t)s * 128 + oct * 8);
    float4 c0 = cp[0], c1 = cp[1], s0 = sp[0], s1 = sp[1];
    float cs[8] = {c0.x,c0.y,c0.z,c0.w,c1.x,c1.y,c1.z,c1.w};
    float sn[8] = {s0.x,s0.y,s0.z,s0.w,s1.x,s1.y,s1.z,s1.w};
    u16x8 ra, rb;
#pragma unroll
    for (int j = 0; j < 8; ++j) {
      float av = b2f(a[j]), bv = b2f(b[j]);
      ra[j] = f2b(av * cs[j] - bv * sn[j]);
      rb[j] = f2b(bv * cs[j] + av * sn[j]);
    }
    *(u16x8*)p1 = ra;
    *(u16x8*)p2 = rb;
  } else {
    int idx = bid - 2560;                    // 512 tiles
    int bs = idx >> 3, bc = idx & 7;
#pragma unroll
    for (int i = 0; i < 2; ++i) {
      int c8 = t + 256 * i;                  // 0..511
      int row = c8 >> 3, cb = c8 & 7;
      u16x8 v = *(const u16x8*)(qkv + (size_t)(bs * 64 + row) * 3072 + 2560 + bc * 64 + cb * 8);
#pragma unroll
      for (int j = 0; j < 8; ++j) tile[row][cb * 8 + j] = v[j];
    }
    __syncthreads();
#pragma unroll
    for (int i = 0; i < 2; ++i) {
      int c8 = t + 256 * i;
      int crow = c8 >> 3, sb = c8 & 7;
      u16x8 v;
#pragma unroll
      for (int j = 0; j < 8; ++j) v[j] = tile[sb * 8 + j][crow];
      *(u16x8*)(vT + (size_t)(bc * 64 + crow) * 4096 + bs * 64 + sb * 8) = v;
    }
  }
}

// ---------------- GEMM C[M,N] = A[M,K] @ B[N,K]^T (bf16 in, bf16/f32 out) --
template <int OUTF32>
__global__ __launch_bounds__(256) void k_gemm_bt(
    const unsigned short* __restrict__ A, const unsigned short* __restrict__ B,
    void* __restrict__ C, int K, int lda, int ldb, int ldc) {
  __shared__ unsigned short As[128 * 64];
  __shared__ unsigned short Bs[128 * 64];
  const int t = threadIdx.x;
  const int lane = t & 63, w = t >> 6;
  const int wm = w >> 1, wn = w & 1;
  const int bn = blockIdx.x, bm = blockIdx.y;
  const unsigned short* Arow = A + (size_t)(bm * 128) * lda;
  const unsigned short* Brow = B + (size_t)(bn * 128) * ldb;

  f32x4 acc[4][4] = {};
  for (int kt = 0; kt < K; kt += 64) {
#pragma unroll
    for (int i = 0; i < 4; ++i) {
      int idx = i * 256 + t;
      int r = idx >> 3, blk = idx & 7;
      int sb = blk ^ (r & 7);
      __builtin_amdgcn_global_load_lds(AS1(Arow + (size_t)r * lda + kt + sb * 8),
                                       AS3(As + (i * 256 + w * 64) * 8), 16, 0, 0);
    }
#pragma unroll
    for (int i = 0; i < 4; ++i) {
      int idx = i * 256 + t;
      int r = idx >> 3, blk = idx & 7;
      int sb = blk ^ (r & 7);
      __builtin_amdgcn_global_load_lds(AS1(Brow + (size_t)r * ldb + kt + sb * 8),
                                       AS3(Bs + (i * 256 + w * 64) * 8), 16, 0, 0);
    }
    __syncthreads();
#pragma unroll
    for (int kk = 0; kk < 2; ++kk) {
      bf16x8 av[4], bv[4];
#pragma unroll
      for (int i = 0; i < 4; ++i) {
        int r = wm * 64 + i * 16 + (lane & 15);
        int off = (r * 128 + (kk * 32 + (lane >> 4) * 8) * 2) ^ ((r & 7) << 4);
        av[i] = *(const bf16x8*)((const char*)As + off);
      }
#pragma unroll
      for (int j = 0; j < 4; ++j) {
        int r = wn * 64 + j * 16 + (lane & 15);
        int off = (r * 128 + (kk * 32 + (lane >> 4) * 8) * 2) ^ ((r & 7) << 4);
        bv[j] = *(const bf16x8*)((const char*)Bs + off);
      }
#pragma unroll
      for (int i = 0; i < 4; ++i)
#pragma unroll
        for (int j = 0; j < 4; ++j)
          acc[i][j] = __builtin_amdgcn_mfma_f32_16x16x32_bf16(av[i], bv[j], acc[i][j], 0, 0, 0);
    }
    __syncthreads();
  }
#pragma unroll
  for (int i = 0; i < 4; ++i)
#pragma unroll
    for (int j = 0; j < 4; ++j)
#pragma unroll
      for (int r = 0; r < 4; ++r) {
        int m = bm * 128 + wm * 64 + i * 16 + (lane >> 4) * 4 + r;
        int n = bn * 128 + wn * 64 + j * 16 + (lane & 15);
        float v = acc[i][j][r];
        if (OUTF32) ((float*)C)[(size_t)m * ldc + n] = v;
        else        ((unsigned short*)C)[(size_t)m * ldc + n] = f2b(v);
      }
}

// ---------------- attention staging helpers (r4-proven) ----------------
__device__ __forceinline__ void stage_k(const unsigned short* __restrict__ qk,
                                        unsigned short* __restrict__ dst,
                                        int kt, int g, int t, int w) {
#pragma unroll
  for (int i = 0; i < 4; ++i) {   // K tile [64 keys][128 d], swz low 3 bits of col16
    int idx = i * 256 + t;
    int r = idx >> 4, blk = idx & 15;
    int sb = (blk & 8) | ((blk ^ r) & 7);
    __builtin_amdgcn_global_load_lds(
        AS1(qk + (size_t)(kt * 64 + r) * 3072 + 2048 + g * 128 + sb * 8),
        AS3(dst + (i * 256 + w * 64) * 8), 16, 0, 0);
  }
}
__device__ __forceinline__ void stage_v(const unsigned short* __restrict__ vT,
                                        unsigned short* __restrict__ dst,
                                        int kt, int g, int t, int w) {
#pragma unroll
  for (int i = 0; i < 4; ++i) {   // V^T tile [128 d][64 keys]
    int idx = i * 256 + t;
    int r = idx >> 3, blk = idx & 7;
    int sb = blk ^ (r & 7);
    __builtin_amdgcn_global_load_lds(
        AS1(vT + (size_t)(g * 128 + r) * 4096 + kt * 64 + sb * 8),
        AS3(dst + (i * 256 + w * 64) * 8), 16, 0, 0);
  }
}

// ---------------- fused causal GQA flash attention ----------------
// r4-proven skeleton (dbuf K/V, one vmcnt(0)+barrier per tile, swapped QK^T,
// register P, masked-tile peel, ph-loop complementary qt pairing) + TWO HEADS
// of the same KV group per block: every K/V ds_read feeds 2 MFMAs -> LDS
// traffic per unit work halved (kernel is LDS-pipe-bound). Grid (32,8) = 256
// blocks = 1/CU, uniform 65 tiles/block regardless of dispatch order.
__global__ __launch_bounds__(256, 1) void k_attn(const unsigned short* __restrict__ qk,
                                                 const unsigned short* __restrict__ vT,
                                                 unsigned short* __restrict__ ctx) {
  __shared__ unsigned short Ks[2][64 * 128];
  __shared__ unsigned short Vs[2][64 * 128];
  const int b = blockIdx.x;                  // 0..31 (qt pair b / 63-b)
  const int hp = blockIdx.y;                 // head pair: heads 2hp, 2hp+1
  const int h0 = hp * 2, g = hp >> 1;        // same KV group for both heads
  const int t = threadIdx.x, lane = t & 63, w = t >> 6;
  const int l15 = lane & 15, lq = lane >> 4;

  for (int ph = 0; ph < 2; ++ph) {
    const int qt = ph ? 63 - b : b;
    const int qg = qt * 64 + w * 16 + l15;   // this lane's softmax q-row (global)

    bf16x8 aq0[4], aq1[4];        // Q fragments, both heads
    {
      const unsigned short* qb =
          qk + (size_t)(qt * 64 + w * 16 + l15) * 3072 + h0 * 128 + lq * 8;
#pragma unroll
      for (int sl = 0; sl < 4; ++sl) {
        aq0[sl] = *(const bf16x8*)(qb + sl * 32);
        aq1[sl] = *(const bf16x8*)(qb + 128 + sl * 32);
      }
    }
    f32x4 o0[8] = {}, o1[8] = {};
    float lsum0 = 0.f, lsum1 = 0.f;

    stage_k(qk, Ks[0], 0, g, t, w);
    stage_v(vT, Vs[0], 0, g, t, w);
    asm volatile("s_waitcnt vmcnt(0)" ::: "memory");
    __builtin_amdgcn_s_barrier();

    auto tile = [&](const unsigned short* Kb, const unsigned short* Vb,
                    int kt, bool maskT) {
      // ---- S^T = K @ Q^T for both heads (shared K read) ----
      f32x4 st0[4] = {}, st1[4] = {};
      __builtin_amdgcn_s_setprio(1);
#pragma unroll
      for (int sl = 0; sl < 4; ++sl)
#pragma unroll
        for (int nt = 0; nt < 4; ++nt) {
          int key = nt * 16 + l15;
          int off = (key * 256 + sl * 64 + lq * 16) ^ ((key & 7) << 4);
          bf16x8 bk = *(const bf16x8*)((const char*)Kb + off);
          st0[nt] = __builtin_amdgcn_mfma_f32_16x16x32_bf16(bk, aq0[sl], st0[nt], 0, 0, 0);
          st1[nt] = __builtin_amdgcn_mfma_f32_16x16x32_bf16(bk, aq1[sl], st1[nt], 0, 0, 0);
        }
      __builtin_amdgcn_s_setprio(0);

      // ---- streaming softmax, in-register (Q pre-scaled, no max) ----
      bf16x4 pa0[4], pa1[4];
#pragma unroll
      for (int nt = 0; nt < 4; ++nt)
#pragma unroll
        for (int r = 0; r < 4; ++r) {
          float p0 = __builtin_amdgcn_exp2f(st0[nt][r]);
          float p1 = __builtin_amdgcn_exp2f(st1[nt][r]);
          if (maskT) {
            int key = kt * 64 + nt * 16 + lq * 4 + r;
            if (key > qg) { p0 = 0.f; p1 = 0.f; }
          }
          lsum0 += p0; lsum1 += p1;
          unsigned int u0 = __builtin_bit_cast(unsigned int, p0) + 0x8000u;
          unsigned int u1 = __builtin_bit_cast(unsigned int, p1) + 0x8000u;
          pa0[nt][r] = (short)(u0 >> 16);
          pa1[nt][r] = (short)(u1 >> 16);
        }

      // ---- O += P @ V for both heads (shared V read) ----
      __builtin_amdgcn_s_setprio(1);
#pragma unroll
      for (int nt = 0; nt < 4; ++nt)
#pragma unroll
        for (int dt = 0; dt < 8; ++dt) {
          int d = dt * 16 + l15;
          int off = (d * 128 + nt * 32 + lq * 8) ^ ((d & 7) << 4);
          bf16x4 vv = *(const bf16x4*)((const char*)Vb + off);
          o0[dt] = mfma16x16x16(pa0[nt], vv, o0[dt]);
          o1[dt] = mfma16x16x16(pa1[nt], vv, o1[dt]);
        }
      __builtin_amdgcn_s_setprio(0);
    };

    for (int kt = 0; kt < qt; ++kt) {        // unmasked main loop
      const int cur = kt & 1;
      stage_k(qk, Ks[cur ^ 1], kt + 1, g, t, w);   // prefetch next tile
      stage_v(vT, Vs[cur ^ 1], kt + 1, g, t, w);
      tile(Ks[cur], Vs[cur], kt, false);
      asm volatile("s_waitcnt vmcnt(0)" ::: "memory");  // prefetch landed
      __builtin_amdgcn_s_barrier();
    }
    {                                        // peeled masked diagonal tile
      tile(Ks[qt & 1], Vs[qt & 1], qt, true);
      __builtin_amdgcn_s_barrier();          // protect buffers for next phase
    }

    // ---- epilogue: row-sum reduce (4 lq-slices), normalize, store ----
    float f0 = lsum0, f1 = lsum1;
    f0 += __shfl_xor(f0, 16); f0 += __shfl_xor(f0, 32);
    f1 += __shfl_xor(f1, 16); f1 += __shfl_xor(f1, 32);
    float iq0[4], iq1[4];
#pragma unroll
    for (int r = 0; r < 4; ++r) {
      iq0[r] = 1.f / __shfl(f0, lq * 4 + r);
      iq1[r] = 1.f / __shfl(f1, lq * 4 + r);
    }
#pragma unroll
    for (int dt = 0; dt < 8; ++dt)
#pragma unroll
      for (int r = 0; r < 4; ++r) {
        int q = qt * 64 + w * 16 + lq * 4 + r;
        int c = h0 * 128 + dt * 16 + l15;
        ctx[(size_t)q * 2048 + c]       = f2b(o0[dt][r] * iq0[r]);
        ctx[(size_t)q * 2048 + c + 128] = f2b(o1[dt][r] * iq1[r]);
      }
  }
}

// ---------------- host ----------------
extern "C" void kernel_launch(void* const* d_in, const int* in_sizes, int n_in,
                              void* d_out, int out_size, void* d_ws, size_t ws_size,
                              hipStream_t stream) {
  const float* x    = (const float*)d_in[0];
  const float* cosb = (const float*)d_in[2];
  const float* sinb = (const float*)d_in[3];
  const float* Wq   = (const float*)d_in[4];
  const float* Wk   = (const float*)d_in[5];
  const float* Wv   = (const float*)d_in[6];
  const float* Wo   = (const float*)d_in[7];

  char* p = (char*)d_ws;
  unsigned short* xb   = (unsigned short*)p; p += (size_t)8388608 * 2;   // x bf16
  unsigned short* wqkv = (unsigned short*)p; p += (size_t)6291456 * 2;   // [3072][2048]
  unsigned short* Wob  = (unsigned short*)p; p += (size_t)4194304 * 2;
  unsigned short* qkvb = (unsigned short*)p; p += (size_t)4096 * 3072 * 2;
  unsigned short* vTb  = (unsigned short*)p; p += (size_t)512 * 4096 * 2;
  unsigned short* ctx  = (unsigned short*)p; p += (size_t)4096 * 2048 * 2;
  if (ws_size < (size_t)(p - (char*)d_ws)) return;

  const float SC = 0.12751741f;   // (1/sqrt(128)) * log2(e), folded into Wq

  k_cvt_all<<<9216, 256, 0, stream>>>(x, Wq, Wk, Wv, Wo, xb, wqkv, Wob, SC);

  // qkv = x @ [Wq;Wk;Wv]^T  -> [4096][3072] (q:0-2047, k:2048-2559, v:2560-3071)
  k_gemm_bt<0><<<dim3(24, 32), 256, 0, stream>>>(xb, wqkv, qkvb, 2048, 2048, 2048, 3072);

  k_post<<<3072, 256, 0, stream>>>(qkvb, cosb, sinb, vTb);

  k_attn<<<dim3(32, 8), 256, 0, stream>>>(qkvb, vTb, ctx);

  k_gemm_bt<1><<<dim3(16, 32), 256, 0, stream>>>(ctx, Wob, d_out, 2048, 2048, 2048, 2048);
}

// Round 10
// 255.004 us; speedup vs baseline: 1.1224x; 1.0336x over previous
//
#include <hip/hip_runtime.h>

typedef __attribute__((ext_vector_type(8))) short bf16x8;     // 8 bf16 in 4 VGPRs
typedef __attribute__((ext_vector_type(4))) short bf16x4;     // 4 bf16 in 2 VGPRs
typedef __attribute__((ext_vector_type(8))) unsigned short u16x8;
typedef __attribute__((ext_vector_type(4))) float f32x4;

__device__ __forceinline__ unsigned short f2b(float f) {      // f32 -> bf16 RNE
  unsigned int u = __builtin_bit_cast(unsigned int, f);
  u += 0x7FFFu + ((u >> 16) & 1u);
  return (unsigned short)(u >> 16);
}
__device__ __forceinline__ float b2f(unsigned short h) {
  return __builtin_bit_cast(float, ((unsigned int)h) << 16);
}

__device__ __forceinline__ f32x4 mfma16x16x16(bf16x4 a, bf16x4 b, f32x4 c) {
#if __has_builtin(__builtin_amdgcn_mfma_f32_16x16x16bf16_1k)
  return __builtin_amdgcn_mfma_f32_16x16x16bf16_1k(a, b, c, 0, 0, 0);
#else
  asm volatile("v_mfma_f32_16x16x16_bf16 %0, %1, %2, %0" : "+v"(c) : "v"(a), "v"(b));
  return c;
#endif
}

#define AS1(p) (const __attribute__((address_space(1))) void*)(p)
#define AS3(p) (__attribute__((address_space(3))) void*)(p)

// ---------------- merged f32 -> bf16 convert (5 segments) ----------------
__device__ __forceinline__ void cvt8(const float* __restrict__ in,
                                     unsigned short* __restrict__ out,
                                     int i, float scale) {
  const float4* p = (const float4*)in + (size_t)i * 2;
  float4 a = p[0], b = p[1];
  u16x8 r;
  r[0] = f2b(a.x * scale); r[1] = f2b(a.y * scale);
  r[2] = f2b(a.z * scale); r[3] = f2b(a.w * scale);
  r[4] = f2b(b.x * scale); r[5] = f2b(b.y * scale);
  r[6] = f2b(b.z * scale); r[7] = f2b(b.w * scale);
  *((u16x8*)out + i) = r;
}

__global__ __launch_bounds__(256) void k_cvt_all(
    const float* __restrict__ x,  const float* __restrict__ Wq,
    const float* __restrict__ Wk, const float* __restrict__ Wv,
    const float* __restrict__ Wo, unsigned short* __restrict__ xb,
    unsigned short* __restrict__ wqkv, unsigned short* __restrict__ Wob,
    float sc) {
  int bid = blockIdx.x;                      // 9216 blocks total, 2048 elems each
  int tid = threadIdx.x;
  if (bid < 4096)      cvt8(x,  xb,             (bid        ) * 256 + tid, 1.f);
  else if (bid < 6144) cvt8(Wq, wqkv,           (bid - 4096) * 256 + tid, sc);
  else if (bid < 6656) cvt8(Wk, wqkv + 4194304, (bid - 6144) * 256 + tid, 1.f);
  else if (bid < 7168) cvt8(Wv, wqkv + 5242880, (bid - 6656) * 256 + tid, 1.f);
  else                 cvt8(Wo, Wob,            (bid - 7168) * 256 + tid, 1.f);
}

// ---------------- merged RoPE (q/k cols) + V transpose ----------------
__global__ __launch_bounds__(256) void k_post(unsigned short* __restrict__ qkv,
                                              const float* __restrict__ cosb,
                                              const float* __restrict__ sinb,
                                              unsigned short* __restrict__ vT) {
  __shared__ unsigned short tile[64][72];
  const int bid = blockIdx.x, t = threadIdx.x;
  if (bid < 2560) {
    int tid = bid * 256 + t;                 // 4096*20*8 = 655360
    int oct = tid & 7;
    int hd  = (tid >> 3) % 20;
    int s   = (tid >> 3) / 20;
    unsigned short* p1 = qkv + (size_t)s * 3072 + hd * 128 + oct * 8;
    unsigned short* p2 = p1 + 64;
    u16x8 a = *(const u16x8*)p1;
    u16x8 b = *(const u16x8*)p2;
    const float4* cp = (const float4*)(cosb + (size_t)s * 128 + oct * 8);
    const float4* sp = (const float4*)(sinb + (size_t)s * 128 + oct * 8);
    float4 c0 = cp[0], c1 = cp[1], s0 = sp[0], s1 = sp[1];
    float cs[8] = {c0.x,c0.y,c0.z,c0.w,c1.x,c1.y,c1.z,c1.w};
    float sn[8] = {s0.x,s0.y,s0.z,s0.w,s1.x,s1.y,s1.z,s1.w};
    u16x8 ra, rb;
#pragma unroll
    for (int j = 0; j < 8; ++j) {
      float av = b2f(a[j]), bv = b2f(b[j]);
      ra[j] = f2b(av * cs[j] - bv * sn[j]);
      rb[j] = f2b(bv * cs[j] + av * sn[j]);
    }
    *(u16x8*)p1 = ra;
    *(u16x8*)p2 = rb;
  } else {
    int idx = bid - 2560;                    // 512 tiles
    int bs = idx >> 3, bc = idx & 7;
#pragma unroll
    for (int i = 0; i < 2; ++i) {
      int c8 = t + 256 * i;                  // 0..511
      int row = c8 >> 3, cb = c8 & 7;
      u16x8 v = *(const u16x8*)(qkv + (size_t)(bs * 64 + row) * 3072 + 2560 + bc * 64 + cb * 8);
#pragma unroll
      for (int j = 0; j < 8; ++j) tile[row][cb * 8 + j] = v[j];
    }
    __syncthreads();
#pragma unroll
    for (int i = 0; i < 2; ++i) {
      int c8 = t + 256 * i;
      int crow = c8 >> 3, sb = c8 & 7;
      u16x8 v;
#pragma unroll
      for (int j = 0; j < 8; ++j) v[j] = tile[sb * 8 + j][crow];
      *(u16x8*)(vT + (size_t)(bc * 64 + crow) * 4096 + bs * 64 + sb * 8) = v;
    }
  }
}

// ---------------- GEMM C[M,N] = A[M,K] @ B[N,K]^T (bf16 in, bf16/f32 out) --
template <int OUTF32>
__global__ __launch_bounds__(256) void k_gemm_bt(
    const unsigned short* __restrict__ A, const unsigned short* __restrict__ B,
    void* __restrict__ C, int K, int lda, int ldb, int ldc) {
  __shared__ unsigned short As[128 * 64];
  __shared__ unsigned short Bs[128 * 64];
  const int t = threadIdx.x;
  const int lane = t & 63, w = t >> 6;
  const int wm = w >> 1, wn = w & 1;
  const int bn = blockIdx.x, bm = blockIdx.y;
  const unsigned short* Arow = A + (size_t)(bm * 128) * lda;
  const unsigned short* Brow = B + (size_t)(bn * 128) * ldb;

  f32x4 acc[4][4] = {};
  for (int kt = 0; kt < K; kt += 64) {
#pragma unroll
    for (int i = 0; i < 4; ++i) {
      int idx = i * 256 + t;
      int r = idx >> 3, blk = idx & 7;
      int sb = blk ^ (r & 7);
      __builtin_amdgcn_global_load_lds(AS1(Arow + (size_t)r * lda + kt + sb * 8),
                                       AS3(As + (i * 256 + w * 64) * 8), 16, 0, 0);
    }
#pragma unroll
    for (int i = 0; i < 4; ++i) {
      int idx = i * 256 + t;
      int r = idx >> 3, blk = idx & 7;
      int sb = blk ^ (r & 7);
      __builtin_amdgcn_global_load_lds(AS1(Brow + (size_t)r * ldb + kt + sb * 8),
                                       AS3(Bs + (i * 256 + w * 64) * 8), 16, 0, 0);
    }
    __syncthreads();
#pragma unroll
    for (int kk = 0; kk < 2; ++kk) {
      bf16x8 av[4], bv[4];
#pragma unroll
      for (int i = 0; i < 4; ++i) {
        int r = wm * 64 + i * 16 + (lane & 15);
        int off = (r * 128 + (kk * 32 + (lane >> 4) * 8) * 2) ^ ((r & 7) << 4);
        av[i] = *(const bf16x8*)((const char*)As + off);
      }
#pragma unroll
      for (int j = 0; j < 4; ++j) {
        int r = wn * 64 + j * 16 + (lane & 15);
        int off = (r * 128 + (kk * 32 + (lane >> 4) * 8) * 2) ^ ((r & 7) << 4);
        bv[j] = *(const bf16x8*)((const char*)Bs + off);
      }
#pragma unroll
      for (int i = 0; i < 4; ++i)
#pragma unroll
        for (int j = 0; j < 4; ++j)
          acc[i][j] = __builtin_amdgcn_mfma_f32_16x16x32_bf16(av[i], bv[j], acc[i][j], 0, 0, 0);
    }
    __syncthreads();
  }
#pragma unroll
  for (int i = 0; i < 4; ++i)
#pragma unroll
    for (int j = 0; j < 4; ++j)
#pragma unroll
      for (int r = 0; r < 4; ++r) {
        int m = bm * 128 + wm * 64 + i * 16 + (lane >> 4) * 4 + r;
        int n = bn * 128 + wn * 64 + j * 16 + (lane & 15);
        float v = acc[i][j][r];
        if (OUTF32) ((float*)C)[(size_t)m * ldc + n] = v;
        else        ((unsigned short*)C)[(size_t)m * ldc + n] = f2b(v);
      }
}

// ---------------- attention staging helpers (r4-proven) ----------------
__device__ __forceinline__ void stage_k(const unsigned short* __restrict__ qk,
                                        unsigned short* __restrict__ dst,
                                        int kt, int g, int t, int w) {
#pragma unroll
  for (int i = 0; i < 4; ++i) {   // K tile [64 keys][128 d], swz low 3 bits of col16
    int idx = i * 256 + t;
    int r = idx >> 4, blk = idx & 15;
    int sb = (blk & 8) | ((blk ^ r) & 7);
    __builtin_amdgcn_global_load_lds(
        AS1(qk + (size_t)(kt * 64 + r) * 3072 + 2048 + g * 128 + sb * 8),
        AS3(dst + (i * 256 + w * 64) * 8), 16, 0, 0);
  }
}
__device__ __forceinline__ void stage_v(const unsigned short* __restrict__ vT,
                                        unsigned short* __restrict__ dst,
                                        int kt, int g, int t, int w) {
#pragma unroll
  for (int i = 0; i < 4; ++i) {   // V^T tile [128 d][64 keys]
    int idx = i * 256 + t;
    int r = idx >> 3, blk = idx & 7;
    int sb = blk ^ (r & 7);
    __builtin_amdgcn_global_load_lds(
        AS1(vT + (size_t)(g * 128 + r) * 4096 + kt * 64 + sb * 8),
        AS3(dst + (i * 256 + w * 64) * 8), 16, 0, 0);
  }
}

// ---------------- fused causal GQA flash attention ----------------
// r9 tile code unchanged (dbuf K/V, swapped QK^T, register P, two heads of
// one KV group per block, masked peel). Balance + TLP via the qt<->block
// mapping: grid (64,8), qt = (by<4) ? bx : 63-bx, hp = by. Bijective over
// (qt, head-pair); under linear dispatch, co-resident blocks c and c+256
// have complementary qt -> every CU's 2 blocks sum to 65 tiles. 2 blocks/CU
// = 8 waves/CU (vs r9's 4): TLP hides the serial QK->softmax->PV chain.
__global__ __launch_bounds__(256, 2) void k_attn(const unsigned short* __restrict__ qk,
                                                 const unsigned short* __restrict__ vT,
                                                 unsigned short* __restrict__ ctx) {
  __shared__ unsigned short Ks[2][64 * 128];
  __shared__ unsigned short Vs[2][64 * 128];
  const int bx = blockIdx.x, by = blockIdx.y;
  const int qt = (by < 4) ? bx : 63 - bx;    // complementary across CU slots
  const int hp = by;                         // head pair: heads 2hp, 2hp+1
  const int h0 = hp * 2, g = hp >> 1;        // same KV group for both heads
  const int t = threadIdx.x, lane = t & 63, w = t >> 6;
  const int l15 = lane & 15, lq = lane >> 4;
  const int qg = qt * 64 + w * 16 + l15;     // this lane's softmax q-row (global)

  bf16x8 aq0[4], aq1[4];          // Q fragments, both heads
  {
    const unsigned short* qb =
        qk + (size_t)(qt * 64 + w * 16 + l15) * 3072 + h0 * 128 + lq * 8;
#pragma unroll
    for (int sl = 0; sl < 4; ++sl) {
      aq0[sl] = *(const bf16x8*)(qb + sl * 32);
      aq1[sl] = *(const bf16x8*)(qb + 128 + sl * 32);
    }
  }
  f32x4 o0[8] = {}, o1[8] = {};
  float lsum0 = 0.f, lsum1 = 0.f;

  stage_k(qk, Ks[0], 0, g, t, w);
  stage_v(vT, Vs[0], 0, g, t, w);
  asm volatile("s_waitcnt vmcnt(0)" ::: "memory");
  __builtin_amdgcn_s_barrier();

  auto tile = [&](const unsigned short* Kb, const unsigned short* Vb,
                  int kt, bool maskT) {
    // ---- S^T = K @ Q^T for both heads (shared K read) ----
    f32x4 st0[4] = {}, st1[4] = {};
    __builtin_amdgcn_s_setprio(1);
#pragma unroll
    for (int sl = 0; sl < 4; ++sl)
#pragma unroll
      for (int nt = 0; nt < 4; ++nt) {
        int key = nt * 16 + l15;
        int off = (key * 256 + sl * 64 + lq * 16) ^ ((key & 7) << 4);
        bf16x8 bk = *(const bf16x8*)((const char*)Kb + off);
        st0[nt] = __builtin_amdgcn_mfma_f32_16x16x32_bf16(bk, aq0[sl], st0[nt], 0, 0, 0);
        st1[nt] = __builtin_amdgcn_mfma_f32_16x16x32_bf16(bk, aq1[sl], st1[nt], 0, 0, 0);
      }
    __builtin_amdgcn_s_setprio(0);

    // ---- streaming softmax, in-register (Q pre-scaled, no max) ----
    bf16x4 pa0[4], pa1[4];
#pragma unroll
    for (int nt = 0; nt < 4; ++nt)
#pragma unroll
      for (int r = 0; r < 4; ++r) {
        float p0 = __builtin_amdgcn_exp2f(st0[nt][r]);
        float p1 = __builtin_amdgcn_exp2f(st1[nt][r]);
        if (maskT) {
          int key = kt * 64 + nt * 16 + lq * 4 + r;
          if (key > qg) { p0 = 0.f; p1 = 0.f; }
        }
        lsum0 += p0; lsum1 += p1;
        unsigned int u0 = __builtin_bit_cast(unsigned int, p0) + 0x8000u;
        unsigned int u1 = __builtin_bit_cast(unsigned int, p1) + 0x8000u;
        pa0[nt][r] = (short)(u0 >> 16);
        pa1[nt][r] = (short)(u1 >> 16);
      }

    // ---- O += P @ V for both heads (shared V read) ----
    __builtin_amdgcn_s_setprio(1);
#pragma unroll
    for (int nt = 0; nt < 4; ++nt)
#pragma unroll
      for (int dt = 0; dt < 8; ++dt) {
        int d = dt * 16 + l15;
        int off = (d * 128 + nt * 32 + lq * 8) ^ ((d & 7) << 4);
        bf16x4 vv = *(const bf16x4*)((const char*)Vb + off);
        o0[dt] = mfma16x16x16(pa0[nt], vv, o0[dt]);
        o1[dt] = mfma16x16x16(pa1[nt], vv, o1[dt]);
      }
    __builtin_amdgcn_s_setprio(0);
  };

  for (int kt = 0; kt < qt; ++kt) {          // unmasked main loop
    const int cur = kt & 1;
    stage_k(qk, Ks[cur ^ 1], kt + 1, g, t, w);   // prefetch next tile
    stage_v(vT, Vs[cur ^ 1], kt + 1, g, t, w);
    tile(Ks[cur], Vs[cur], kt, false);
    asm volatile("s_waitcnt vmcnt(0)" ::: "memory");  // prefetch landed
    __builtin_amdgcn_s_barrier();
  }
  tile(Ks[qt & 1], Vs[qt & 1], qt, true);    // peeled masked diagonal tile

  // ---- epilogue: row-sum reduce (4 lq-slices), normalize, store ----
  float f0 = lsum0, f1 = lsum1;
  f0 += __shfl_xor(f0, 16); f0 += __shfl_xor(f0, 32);
  f1 += __shfl_xor(f1, 16); f1 += __shfl_xor(f1, 32);
  float iq0[4], iq1[4];
#pragma unroll
  for (int r = 0; r < 4; ++r) {
    iq0[r] = 1.f / __shfl(f0, lq * 4 + r);
    iq1[r] = 1.f / __shfl(f1, lq * 4 + r);
  }
#pragma unroll
  for (int dt = 0; dt < 8; ++dt)
#pragma unroll
    for (int r = 0; r < 4; ++r) {
      int q = qt * 64 + w * 16 + lq * 4 + r;
      int c = h0 * 128 + dt * 16 + l15;
      ctx[(size_t)q * 2048 + c]       = f2b(o0[dt][r] * iq0[r]);
      ctx[(size_t)q * 2048 + c + 128] = f2b(o1[dt][r] * iq1[r]);
    }
}

// ---------------- host ----------------
extern "C" void kernel_launch(void* const* d_in, const int* in_sizes, int n_in,
                              void* d_out, int out_size, void* d_ws, size_t ws_size,
                              hipStream_t stream) {
  const float* x    = (const float*)d_in[0];
  const float* cosb = (const float*)d_in[2];
  const float* sinb = (const float*)d_in[3];
  const float* Wq   = (const float*)d_in[4];
  const float* Wk   = (const float*)d_in[5];
  const float* Wv   = (const float*)d_in[6];
  const float* Wo   = (const float*)d_in[7];

  char* p = (char*)d_ws;
  unsigned short* xb   = (unsigned short*)p; p += (size_t)8388608 * 2;   // x bf16
  unsigned short* wqkv = (unsigned short*)p; p += (size_t)6291456 * 2;   // [3072][2048]
  unsigned short* Wob  = (unsigned short*)p; p += (size_t)4194304 * 2;
  unsigned short* qkvb = (unsigned short*)p; p += (size_t)4096 * 3072 * 2;
  unsigned short* vTb  = (unsigned short*)p; p += (size_t)512 * 4096 * 2;
  unsigned short* ctx  = (unsigned short*)p; p += (size_t)4096 * 2048 * 2;
  if (ws_size < (size_t)(p - (char*)d_ws)) return;

  const float SC = 0.12751741f;   // (1/sqrt(128)) * log2(e), folded into Wq

  k_cvt_all<<<9216, 256, 0, stream>>>(x, Wq, Wk, Wv, Wo, xb, wqkv, Wob, SC);

  // qkv = x @ [Wq;Wk;Wv]^T  -> [4096][3072] (q:0-2047, k:2048-2559, v:2560-3071)
  k_gemm_bt<0><<<dim3(24, 32), 256, 0, stream>>>(xb, wqkv, qkvb, 2048, 2048, 2048, 3072);

  k_post<<<3072, 256, 0, stream>>>(qkvb, cosb, sinb, vTb);

  k_attn<<<dim3(64, 8), 256, 0, stream>>>(qkvb, vTb, ctx);

  k_gemm_bt<1><<<dim3(16, 32), 256, 0, stream>>>(ctx, Wob, d_out, 2048, 2048, 2048, 2048);
}